// Round 2
// 64.216 us; speedup vs baseline: 1.0065x; 1.0065x over previous
//
#include <hip/hip_runtime.h>

// Closed form of the 16-qubit circuit:
//   ev[b,i] = prod_{k in S_i} cos(h[b,k]),  S_i = {k<=i : (i-k) mod 4 in {0,1}}
// where h = x@w_in^T + b_in. RZ phases (q_weights) cancel in |amp|^2
// (diagonal unitaries + basis permutation only); the CNOT-chain applied 3x is
// the GF(2) map L^3 with (L^3)_{ik}=1 iff (i-k) mod 4 in {0,1}. Parity
// expectation of independent RY qubits = product of cos(h_k).
// out = ev @ w_out^T + b_out. All float32.
//
// ONE WAVE PER ROW, no LDS, no __syncthreads:
//   - 4 lanes per qubit each do a 32-elem float4 dot of x-row . w_in[q,:]
//   - butterfly __shfl_xor(1),(2) completes the 128-dot within the 4-lane group
//   - cosf computed redundantly by all 4 lanes (SIMT-free)
//   - the 16 cosines are broadcast to all lanes via v_readlane (const lane idx)
//   - ev via the recurrence ev[i] = c[i]*c[i-1]*ev[i-4]  (S_i structure)
//   - each lane writes 2 output columns (t = lane, lane+64), float4 w_out loads
// Straight-line latency chain, all 512 waves concurrent (1 wave/SIMD chip-wide).

#define NQ 16
#define D  128

__global__ __launch_bounds__(64) void qlayer_kernel(
    const float* __restrict__ x,      // [B, 128]
    const float* __restrict__ w_in,   // [16, 128]
    const float* __restrict__ b_in,   // [16]
    const float* __restrict__ w_out,  // [128, 16]
    const float* __restrict__ b_out,  // [128]
    float* __restrict__ out)          // [B, 128]
{
    const int b   = blockIdx.x;
    const int l   = threadIdx.x;   // 0..63
    const int g   = l >> 2;        // qubit 0..15
    const int sub = l & 3;         // quarter of the 128-dot, 0..3

    // --- h_g partial: 32 consecutive elems, float4-vectorized ---
    const float4* xv = reinterpret_cast<const float4*>(x + b * D + sub * 32);
    const float4* wv = reinterpret_cast<const float4*>(w_in + g * D + sub * 32);
    float p = 0.f;
#pragma unroll
    for (int k = 0; k < 8; ++k) {
        float4 a = xv[k];
        float4 w = wv[k];
        p += a.x * w.x + a.y * w.y + a.z * w.z + a.w * w.w;
    }
    // complete the dot within the 4-lane group (no LDS, no barrier)
    p += __shfl_xor(p, 1);
    p += __shfl_xor(p, 2);

    const float c = cosf(p + b_in[g]);  // all 4 lanes of the group agree

    // --- broadcast the 16 per-qubit cosines to every lane ---
    float cc[NQ];
#pragma unroll
    for (int k = 0; k < NQ; ++k)
        cc[k] = __uint_as_float(
            __builtin_amdgcn_readlane(__float_as_uint(c), k << 2));

    // --- ev[i] = prod_{k in S_i} cc[k] via ev[i] = cc[i]*cc[i-1]*ev[i-4] ---
    float ev[NQ];
    ev[0] = cc[0];
    ev[1] = cc[1] * cc[0];
    ev[2] = cc[2] * cc[1];
    ev[3] = cc[3] * cc[2];
#pragma unroll
    for (int i = 4; i < NQ; ++i)
        ev[i] = cc[i] * cc[i - 1] * ev[i - 4];

    // --- out[b, t] = b_out[t] + sum_q ev[q] * w_out[t, q], two cols per lane ---
#pragma unroll
    for (int rep = 0; rep < 2; ++rep) {
        const int t = l + rep * 64;
        const float4* wo = reinterpret_cast<const float4*>(w_out + t * NQ);
        float o = b_out[t];
#pragma unroll
        for (int q4 = 0; q4 < 4; ++q4) {
            float4 w = wo[q4];
            o += ev[q4 * 4 + 0] * w.x + ev[q4 * 4 + 1] * w.y
               + ev[q4 * 4 + 2] * w.z + ev[q4 * 4 + 3] * w.w;
        }
        out[b * D + t] = o;
    }
}

extern "C" void kernel_launch(void* const* d_in, const int* in_sizes, int n_in,
                              void* d_out, int out_size, void* d_ws, size_t ws_size,
                              hipStream_t stream) {
    const float* x     = (const float*)d_in[0];  // [512,128]
    const float* w_in  = (const float*)d_in[1];  // [16,128]
    const float* b_in  = (const float*)d_in[2];  // [16]
    // d_in[3] = q_weights — unused: RZ phases cancel in Z-basis probabilities.
    const float* w_out = (const float*)d_in[4];  // [128,16]
    const float* b_out = (const float*)d_in[5];  // [128]
    float* out = (float*)d_out;                  // [512,128]

    // in_sizes are ELEMENT COUNTS (verified: previous passing kernel used this).
    const int rows = in_sizes[0] / D;  // 65536 / 128 = 512
    qlayer_kernel<<<rows, 64, 0, stream>>>(x, w_in, b_in, w_out, b_out, out);
}